// Round 5
// baseline (1119.319 us; speedup 1.0000x reference)
//
#include <hip/hip_runtime.h>

typedef _Float16 half8_t __attribute__((ext_vector_type(8)));
typedef float floatx4 __attribute__((ext_vector_type(4)));

#define B_DIM 256
#define T_DIM 512
#define E_DIM 256
#define H_DIM 256
#define MROWS (B_DIM * T_DIM)  // 131072 rows of [B*T, E]

// 1 KB wave-cooperative global->LDS DMA: lane i copies bytes [16i,16i+16).
__device__ __forceinline__ void dma1k(const void* g, void* l, int lane) {
    __builtin_amdgcn_global_load_lds(
        (const __attribute__((address_space(1))) unsigned int*)
            ((const char*)g + lane * 16),
        (__attribute__((address_space(3))) unsigned int*)l,
        16, 0, 0);
}

// ---------------------------------------------------------------------------
// Phase 1: X[m][n] = emb[m][:E] . Wg[n][:E] + bg[n]  for gates g in {z,r,m}
// One block per 128-row m-tile; loops the 6 gate/n-tiles INSIDE so the emb
// tile is read from HBM once and re-read L2-hot (was 6x HBM). Otherwise the
// verified R0 structure: f16 MFMA 16x16x32, 128x128 tiles, BK=32.
// ---------------------------------------------------------------------------
__global__ __launch_bounds__(256, 2) void gemm_x(
    const float* __restrict__ emb,
    const float* __restrict__ Wz, const float* __restrict__ bz,
    const float* __restrict__ Wr, const float* __restrict__ br,
    const float* __restrict__ Wm, const float* __restrict__ bm,
    _Float16* __restrict__ Xz, _Float16* __restrict__ Xr,
    float* __restrict__ Xm)
{
    const int m0 = blockIdx.x * 128;

    // padded row stride 40 halves (80 B): 16B-aligned rows, <=2-way bank alias
    __shared__ __align__(16) _Float16 lA[128 * 40];
    __shared__ __align__(16) _Float16 lB[128 * 40];

    const int t = threadIdx.x;
    const int lane = t & 63;
    const int wave = t >> 6;
    const int wm = (wave >> 1) * 64;
    const int wn = (wave & 1) * 64;
    const int lq = lane >> 4;               // quad
    const int lr = lane & 15;

    const int srow = t >> 1;                // 0..127
    const int scol = (t & 1) * 16;          // 0 or 16 (halves within 32-k tile)
    const float* aSrc = emb + (size_t)(m0 + srow) * E_DIM + scol;

    for (int nt = 0; nt < 6; ++nt) {
        const int gate = nt >> 1;
        const int ng0 = (nt & 1) * 128;
        const float* W    = (gate == 0) ? Wz : (gate == 1) ? Wr : Wm;
        const float* bias = (gate == 0) ? bz : (gate == 1) ? br : bm;
        const float* bSrc = W + (size_t)(ng0 + srow) * (E_DIM + H_DIM) + scol;

        floatx4 acc[4][4];
        #pragma unroll
        for (int i = 0; i < 4; ++i)
            #pragma unroll
            for (int j = 0; j < 4; ++j)
                acc[i][j] = (floatx4)0.0f;

        for (int k0 = 0; k0 < E_DIM; k0 += 32) {
            float ta[16], tb[16];
            #pragma unroll
            for (int u = 0; u < 4; ++u) {
                *(float4*)(ta + 4 * u) = *(const float4*)(aSrc + k0 + 4 * u);
                *(float4*)(tb + 4 * u) = *(const float4*)(bSrc + k0 + 4 * u);
            }
            half8_t a0, a1, b0, b1;
            #pragma unroll
            for (int u = 0; u < 8; ++u) {
                a0[u] = (_Float16)ta[u]; a1[u] = (_Float16)ta[u + 8];
                b0[u] = (_Float16)tb[u]; b1[u] = (_Float16)tb[u + 8];
            }
            __syncthreads();   // previous iter's LDS reads done
            *(half8_t*)&lA[srow * 40 + scol]     = a0;
            *(half8_t*)&lA[srow * 40 + scol + 8] = a1;
            *(half8_t*)&lB[srow * 40 + scol]     = b0;
            *(half8_t*)&lB[srow * 40 + scol + 8] = b1;
            __syncthreads();

            half8_t af[4], bf[4];
            #pragma unroll
            for (int i = 0; i < 4; ++i)
                af[i] = *(const half8_t*)&lA[(wm + i * 16 + lr) * 40 + lq * 8];
            #pragma unroll
            for (int j = 0; j < 4; ++j)
                bf[j] = *(const half8_t*)&lB[(wn + j * 16 + lr) * 40 + lq * 8];
            #pragma unroll
            for (int i = 0; i < 4; ++i)
                #pragma unroll
                for (int j = 0; j < 4; ++j)
                    acc[i][j] = __builtin_amdgcn_mfma_f32_16x16x32_f16(
                        af[i], bf[j], acc[i][j], 0, 0, 0);
        }

        // epilogue: D[row=(lane>>4)*4+r][col=lane&15], add bias, store
        if (gate < 2) {
            _Float16* dst = (gate == 0) ? Xz : Xr;
            #pragma unroll
            for (int j = 0; j < 4; ++j) {
                const int ng = ng0 + wn + j * 16 + lr;
                const float bv = bias[ng];
                #pragma unroll
                for (int i = 0; i < 4; ++i) {
                    const int mrow = m0 + wm + i * 16 + lq * 4;
                    #pragma unroll
                    for (int r = 0; r < 4; ++r)
                        dst[(size_t)(mrow + r) * H_DIM + ng] =
                            (_Float16)(acc[i][j][r] + bv);
                }
            }
        } else {
            #pragma unroll
            for (int j = 0; j < 4; ++j) {
                const int ng = ng0 + wn + j * 16 + lr;
                const float bv = bias[ng];
                #pragma unroll
                for (int i = 0; i < 4; ++i) {
                    const int mrow = m0 + wm + i * 16 + lq * 4;
                    #pragma unroll
                    for (int r = 0; r < 4; ++r)
                        Xm[(size_t)(mrow + r) * H_DIM + ng] = acc[i][j][r] + bv;
                }
            }
        }
    }
}

// ---------------------------------------------------------------------------
// Phase 2: persistent recurrence, MFMA matvec, 16 waves (1024 threads).
// One WG per batch element, 256 WGs = 256 CUs.
//
// 16-wave split: per-wave weights = af[2][8] (64 VGPR) + am[8] (32 VGPR),
// total ~125 VGPR <= 128 cap at 4 waves/SIMD -> A-fragments stay in real
// VGPRs (R2/R4's 8-wave version needed 192 regs of weights -> AGPR, and
// VALUBusy ~29% matched per-MFMA accvgpr_read shuffling). Also: epilogue
// work per wave halves; 4 waves/SIMD give finer MFMA/VALU skew.
//
// Work map per step:
//   phase A: gate g=w>>3 (0=z,1=r); wave handles m-tiles (w&7)*2+{0,1}
//            -> 16 MFMA/wave; epilogue lanes lr<8 own rows (w&7)*32..+31.
//   phase B: m-gate; wave handles m-tile w -> 8 MFMA/wave; epilogue lanes
//            lr<4 own rows w*16..+15.
// X staged in LDS via global_load_lds (16 x 1KB chunks, one per wave),
// double-buffered per 8 steps; h flushed from LDS hist once per 8 steps.
// ---------------------------------------------------------------------------
__device__ __forceinline__ float pick4(floatx4 v, int r) {
    float x01 = (r & 1) ? v[1] : v[0];
    float x23 = (r & 1) ? v[3] : v[2];
    return (r & 2) ? x23 : x01;
}

__global__ __launch_bounds__(1024, 1) void gru_rec(
    const float* __restrict__ Wz,
    const float* __restrict__ Wr,
    const float* __restrict__ Wm,
    const _Float16* __restrict__ Xz,
    const _Float16* __restrict__ Xr,
    float* __restrict__ out)   // holds Xm on entry per row; overwritten with h
{
    const int b = blockIdx.x;
    const int t = threadIdx.x;
    const int w    = t >> 6;        // wave 0..15
    const int lane = t & 63;
    const int lr   = lane & 15;     // D column / A row-in-tile
    const int lq   = lane >> 4;     // D row-quad / A k-octet

    __shared__ __align__(16) _Float16 hh[256];   // h as f16 (MFMA B operand)
    __shared__ __align__(16) float    hf[256];   // h master fp32
    __shared__ __align__(16) _Float16 rh[256];   // r*h as f16
    __shared__ __align__(16) float    zl[256];   // z gate values
    __shared__ __align__(16) _Float16 xzS[4096]; // 2 bufs x 8 rows x 256 (8 KB)
    __shared__ __align__(16) _Float16 xrS[4096]; // 8 KB
    __shared__ __align__(16) float    xmS[4096]; // 16 KB
    __shared__ __align__(16) float    hist[2048];// 8 steps x 256 h rows (8 KB)

    // ---- load recurrent-weight A fragments into registers (fp32 -> f16) ----
    half8_t af[2][8];   // phase A: gate w>>3, m-tiles (w&7)*2 + i
    {
        const float* Wg = (w < 8) ? Wz : Wr;
        #pragma unroll
        for (int i = 0; i < 2; ++i) {
            const float* rp = Wg +
                (size_t)(((w & 7) * 2 + i) * 16 + lr) * (E_DIM + H_DIM) +
                E_DIM + lq * 8;
            #pragma unroll
            for (int kt = 0; kt < 8; ++kt) {
                float4 f0 = *(const float4*)(rp + kt * 32);
                float4 f1 = *(const float4*)(rp + kt * 32 + 4);
                half8_t hv;
                hv[0] = (_Float16)f0.x; hv[1] = (_Float16)f0.y;
                hv[2] = (_Float16)f0.z; hv[3] = (_Float16)f0.w;
                hv[4] = (_Float16)f1.x; hv[5] = (_Float16)f1.y;
                hv[6] = (_Float16)f1.z; hv[7] = (_Float16)f1.w;
                af[i][kt] = hv;
            }
        }
    }
    half8_t am[8];      // phase B: m gate, m-tile w
    {
        const float* rp = Wm +
            (size_t)(w * 16 + lr) * (E_DIM + H_DIM) + E_DIM + lq * 8;
        #pragma unroll
        for (int kt = 0; kt < 8; ++kt) {
            float4 f0 = *(const float4*)(rp + kt * 32);
            float4 f1 = *(const float4*)(rp + kt * 32 + 4);
            half8_t hv;
            hv[0] = (_Float16)f0.x; hv[1] = (_Float16)f0.y;
            hv[2] = (_Float16)f0.z; hv[3] = (_Float16)f0.w;
            hv[4] = (_Float16)f1.x; hv[5] = (_Float16)f1.y;
            hv[6] = (_Float16)f1.z; hv[7] = (_Float16)f1.w;
            am[kt] = hv;
        }
    }

    // per-lane output-row ownership
    //   phase A (lanes lr<8): i=(lr>>2)&1, r=lr&3 -> rows [(w&7)*32, +32)
    const int rowA = (w & 7) * 32 + ((lr >> 2) & 1) * 16 + lq * 4 + (lr & 3);
    //   phase B (lanes lr<4): r=lr -> rows [w*16, +16)
    const int rowB = w * 16 + lq * 4 + (lr & 3);

    const size_t rowbase = (size_t)b * T_DIM * H_DIM;
    const _Float16* XgS = (w < 8) ? xzS : xrS;   // LDS stage source per wave

    // stage rows [row0, row0+8) of Xz/Xr/out into LDS buffer `buf`.
    // 16 x 1KB DMA chunks, exactly one per wave (wave-uniform branch).
    auto stage_block = [&](int row0, int buf) {
        const size_t base = rowbase + (size_t)row0 * H_DIM;  // element offset
        const int q = w;
        if (q < 4)
            dma1k(Xz + base + q * 512,
                  (void*)(xzS + buf * 2048 + q * 512), lane);
        else if (q < 8)
            dma1k(Xr + base + (q - 4) * 512,
                  (void*)(xrS + buf * 2048 + (q - 4) * 512), lane);
        else
            dma1k(out + base + (q - 8) * 256,
                  (void*)(xmS + buf * 2048 + (q - 8) * 256), lane);
    };

    stage_block(0, 0);                       // rows 0..7 -> buf 0
    if (t < 256) { hh[t] = (_Float16)0.0f; hf[t] = 0.0f; }
    __syncthreads();                         // drains prologue DMA (once)

    for (int ts8 = 0; ts8 < T_DIM; ts8 += 8) {
        const int cur = (ts8 >> 3) & 1;
        #pragma unroll
        for (int j = 0; j < 8; ++j) {
            // issue next block's staging early in step 7; drained (hidden)
            // under this step's phase-A MFMAs at the phase-A barrier.
            if (j == 7 && ts8 + 8 < T_DIM)
                stage_block(ts8 + 8, cur ^ 1);

            // ---- phase A: (Wz_h.h | Wr_h.h) via MFMA, then sigmoid ----
            floatx4 acc0 = (floatx4)0.0f, acc1 = (floatx4)0.0f;
            #pragma unroll
            for (int kt = 0; kt < 8; ++kt) {
                half8_t bf = *(const half8_t*)&hh[kt * 32 + lq * 8]; // bcast/lq
                acc0 = __builtin_amdgcn_mfma_f32_16x16x32_f16(
                    af[0][kt], bf, acc0, 0, 0, 0);
                acc1 = __builtin_amdgcn_mfma_f32_16x16x32_f16(
                    af[1][kt], bf, acc1, 0, 0, 0);
            }
            if (lr < 8) {
                const int r = lr & 3;
                float s0 = pick4(acc0, r), s1 = pick4(acc1, r);
                float v = (lr & 4) ? s1 : s0;
                const float a = v + (float)XgS[cur * 2048 + j * 256 + rowA];
                const float g = 1.0f / (1.0f + __expf(-a));
                if (w < 8) zl[rowA] = g;                        // z
                else       rh[rowA] = (_Float16)(g * hf[rowA]); // r*h
            }
            __syncthreads();

            // ---- phase B: Wm_h.(r*h) via MFMA, then tanh + h update ----
            floatx4 acc2 = (floatx4)0.0f;
            #pragma unroll
            for (int kt = 0; kt < 8; ++kt) {
                half8_t bfm = *(const half8_t*)&rh[kt * 32 + lq * 8];
                acc2 = __builtin_amdgcn_mfma_f32_16x16x32_f16(
                    am[kt], bfm, acc2, 0, 0, 0);
            }
            if (lr < 4) {
                const float v2  = pick4(acc2, lr & 3);
                const float amv = v2 + xmS[cur * 2048 + j * 256 + rowB];
                const float hc  = 2.0f / (1.0f + __expf(-2.0f * amv)) - 1.0f;
                const float z   = zl[rowB];
                const float hp  = hf[rowB];
                const float hn  = hp + z * (hc - hp);
                hist[j * 256 + rowB] = hn;
                hf[rowB] = hn;
                hh[rowB] = (_Float16)hn;
            }
            __syncthreads();
        }

        // ---- batched h flush: hist is the flat image of out rows ts8..+7 ----
        {
            const float2 hv2 = *(const float2*)&hist[t * 2];
            *(float2*)&out[rowbase + (size_t)ts8 * H_DIM + t * 2] = hv2;
        }
    }
}

extern "C" void kernel_launch(void* const* d_in, const int* in_sizes, int n_in,
                              void* d_out, int out_size, void* d_ws, size_t ws_size,
                              hipStream_t stream) {
    (void)in_sizes; (void)n_in; (void)out_size; (void)ws_size;
    const float* emb = (const float*)d_in[0];
    const float* Wz  = (const float*)d_in[1];
    const float* bz  = (const float*)d_in[2];
    const float* Wr  = (const float*)d_in[3];
    const float* br  = (const float*)d_in[4];
    const float* Wm  = (const float*)d_in[5];
    const float* bm  = (const float*)d_in[6];
    float* out = (float*)d_out;

    _Float16* Xz = (_Float16*)d_ws;                      // [131072][256] f16
    _Float16* Xr = Xz + (size_t)MROWS * H_DIM;           // [131072][256] f16

    dim3 g1(MROWS / 128);
    gemm_x<<<g1, 256, 0, stream>>>(emb, Wz, bz, Wr, br, Wm, bm, Xz, Xr, out);
    gru_rec<<<B_DIM, 1024, 0, stream>>>(Wz, Wr, Wm, Xz, Xr, out);
}

// Round 8
// 1005.959 us; speedup vs baseline: 1.1127x; 1.1127x over previous
//
#include <hip/hip_runtime.h>

typedef _Float16 half8_t __attribute__((ext_vector_type(8)));
typedef _Float16 half4_t __attribute__((ext_vector_type(4)));
typedef float floatx4 __attribute__((ext_vector_type(4)));

#define B_DIM 256
#define T_DIM 512
#define E_DIM 256
#define H_DIM 256
#define MROWS (B_DIM * T_DIM)  // 131072 rows of [B*T, E]

// 1 KB wave-cooperative global->LDS DMA: lane i copies bytes [16i,16i+16).
__device__ __forceinline__ void dma1k(const void* g, void* l, int lane) {
    __builtin_amdgcn_global_load_lds(
        (const __attribute__((address_space(1))) unsigned int*)
            ((const char*)g + lane * 16),
        (__attribute__((address_space(3))) unsigned int*)l,
        16, 0, 0);
}

// ---------------------------------------------------------------------------
// Phase 0: one-shot fp32 -> f16 conversion of the three W matrices (1.5 MB),
// so the 1024 gemm blocks don't each redo it. grid (128, 3) x 256 thr.
// ---------------------------------------------------------------------------
__global__ void cvt_w(const float* __restrict__ Wz,
                      const float* __restrict__ Wr,
                      const float* __restrict__ Wm,
                      _Float16* __restrict__ Wf16)
{
    const int g = blockIdx.y;
    const float* W = (g == 0) ? Wz : (g == 1) ? Wr : Wm;
    const size_t i4 = ((size_t)blockIdx.x * 256 + threadIdx.x) * 4; // < 131072*4
    float4 f = *(const float4*)(W + i4);
    half4_t h;
    h[0] = (_Float16)f.x; h[1] = (_Float16)f.y;
    h[2] = (_Float16)f.z; h[3] = (_Float16)f.w;
    *(half4_t*)(Wf16 + (size_t)g * (256 * 512) + i4) = h;
}

// ---------------------------------------------------------------------------
// Phase 1: X[m][n] = emb[m][:E] . Wg[n][:E] + bg[n]  for gates g in {z,r,m}
// v2: one block per 128-row m-tile (grid 1024, 1 block/CU). The A-tile
// (emb, fp32->f16) is staged ONCE into a full-K 64 KB LDS tile; the 6
// gate/n-tiles loop inside, staging B as f16 (pre-converted by cvt_w; fp32
// cvt fallback if workspace is tight). Both LDS tiles use the T2 XOR
// swizzle (stride 512 B, byte ^= (row&7)<<4) -> conflict-free ds_read_b128.
// 13 barriers/block (was 97), zero cvt in the hot loop (was 1536/thread).
// ---------------------------------------------------------------------------
__global__ __launch_bounds__(256, 1) void gemm_x(
    const float* __restrict__ emb,
    const float* __restrict__ Wz, const float* __restrict__ bz,
    const float* __restrict__ Wr, const float* __restrict__ br,
    const float* __restrict__ Wm, const float* __restrict__ bm,
    const _Float16* __restrict__ Wf16,     // may be null -> fp32 fallback
    _Float16* __restrict__ Xz, _Float16* __restrict__ Xr,
    float* __restrict__ Xm)
{
    const int m0 = blockIdx.x * 128;

    __shared__ __align__(16) _Float16 lA[128 * 256];  // 64 KB, swizzled
    __shared__ __align__(16) _Float16 lB[128 * 256];  // 64 KB, swizzled

    const int t = threadIdx.x;
    const int lane = t & 63;
    const int wave = t >> 6;
    const int wm = (wave >> 1) * 64;
    const int wn = (wave & 1) * 64;
    const int lq = lane >> 4;               // k-octet within 32-k step
    const int lr = lane & 15;               // row-in-tile / D column

    // ---- stage A once: 128 x 256 fp32 -> f16, swizzled ----
    {
        const int row  = t >> 1;
        const int colb = (t & 1) * 128;     // f16 column base
        const float* src = emb + (size_t)(m0 + row) * E_DIM + colb;
        char* dst = (char*)lA + row * 512;
        const int sw = (row & 7) << 4;
        #pragma unroll
        for (int c = 0; c < 16; ++c) {
            float4 f0 = *(const float4*)(src + c * 8);
            float4 f1 = *(const float4*)(src + c * 8 + 4);
            half8_t hv;
            hv[0] = (_Float16)f0.x; hv[1] = (_Float16)f0.y;
            hv[2] = (_Float16)f0.z; hv[3] = (_Float16)f0.w;
            hv[4] = (_Float16)f1.x; hv[5] = (_Float16)f1.y;
            hv[6] = (_Float16)f1.z; hv[7] = (_Float16)f1.w;
            *(half8_t*)(dst + (((colb + c * 8) * 2) ^ sw)) = hv;
        }
    }
    __syncthreads();

    const int swf = (lr & 7) << 4;          // frag-read swizzle (row&7 == lr&7)

    for (int nt = 0; nt < 6; ++nt) {
        const int gate = nt >> 1;
        const int ng0 = (nt & 1) * 128;
        const float* bias = (gate == 0) ? bz : (gate == 1) ? br : bm;

        // ---- stage B: 128 x 256 f16 (or fp32+cvt fallback), swizzled ----
        {
            const int row  = t >> 1;
            const int colb = (t & 1) * 128;
            char* dst = (char*)lB + row * 512;
            const int sw = (row & 7) << 4;
            if (Wf16) {
                const _Float16* src = Wf16 + (size_t)gate * (256 * 512) +
                                      (size_t)(ng0 + row) * 512 + colb;
                #pragma unroll
                for (int c = 0; c < 16; ++c)
                    *(half8_t*)(dst + (((colb + c * 8) * 2) ^ sw)) =
                        *(const half8_t*)(src + c * 8);
            } else {
                const float* W = (gate == 0) ? Wz : (gate == 1) ? Wr : Wm;
                const float* src = W + (size_t)(ng0 + row) * 512 + colb;
                #pragma unroll
                for (int c = 0; c < 16; ++c) {
                    float4 f0 = *(const float4*)(src + c * 8);
                    float4 f1 = *(const float4*)(src + c * 8 + 4);
                    half8_t hv;
                    hv[0] = (_Float16)f0.x; hv[1] = (_Float16)f0.y;
                    hv[2] = (_Float16)f0.z; hv[3] = (_Float16)f0.w;
                    hv[4] = (_Float16)f1.x; hv[5] = (_Float16)f1.y;
                    hv[6] = (_Float16)f1.z; hv[7] = (_Float16)f1.w;
                    *(half8_t*)(dst + (((colb + c * 8) * 2) ^ sw)) = hv;
                }
            }
        }
        __syncthreads();

        floatx4 acc[4][4];
        #pragma unroll
        for (int i = 0; i < 4; ++i)
            #pragma unroll
            for (int j = 0; j < 4; ++j)
                acc[i][j] = (floatx4)0.0f;

        #pragma unroll
        for (int k0 = 0; k0 < 8; ++k0) {
            const int kb = k0 * 64 + lq * 16;   // byte col offset of 8 f16
            half8_t af[4], bf[4];
            #pragma unroll
            for (int i = 0; i < 4; ++i)
                af[i] = *(const half8_t*)
                    ((const char*)lA + (wm + i * 16 + lr) * 512 + (kb ^ swf));
            #pragma unroll
            for (int j = 0; j < 4; ++j)
                bf[j] = *(const half8_t*)
                    ((const char*)lB + (wn + j * 16 + lr) * 512 + (kb ^ swf));
            #pragma unroll
            for (int i = 0; i < 4; ++i)
                #pragma unroll
                for (int j = 0; j < 4; ++j)
                    acc[i][j] = __builtin_amdgcn_mfma_f32_16x16x32_f16(
                        af[i], bf[j], acc[i][j], 0, 0, 0);
        }

        // epilogue: D[row=(lane>>4)*4+r][col=lane&15], add bias, store
        if (gate < 2) {
            _Float16* dst = (gate == 0) ? Xz : Xr;
            #pragma unroll
            for (int j = 0; j < 4; ++j) {
                const int ng = ng0 + wn + j * 16 + lr;
                const float bv = bias[ng];
                #pragma unroll
                for (int i = 0; i < 4; ++i) {
                    const int mrow = m0 + wm + i * 16 + lq * 4;
                    #pragma unroll
                    for (int r = 0; r < 4; ++r)
                        dst[(size_t)(mrow + r) * H_DIM + ng] =
                            (_Float16)(acc[i][j][r] + bv);
                }
            }
        } else {
            #pragma unroll
            for (int j = 0; j < 4; ++j) {
                const int ng = ng0 + wn + j * 16 + lr;
                const float bv = bias[ng];
                #pragma unroll
                for (int i = 0; i < 4; ++i) {
                    const int mrow = m0 + wm + i * 16 + lq * 4;
                    #pragma unroll
                    for (int r = 0; r < 4; ++r)
                        Xm[(size_t)(mrow + r) * H_DIM + ng] = acc[i][j][r] + bv;
                }
            }
        }
        __syncthreads();
    }
}

// ---------------------------------------------------------------------------
// Phase 2: persistent recurrence, MFMA matvec, 8 waves — EXACT R4 version
// (builtin MFMA, measured 780 us). One WG per batch, 256 WGs = 256 CUs.
//   phase A: waves 0-3 = z-gate, waves 4-7 = r-gate; af[4][8], 32 MFMA/wave;
//            all 64 lanes own one row each (rowA).
//   phase B: m-gate; am[2][8], 16 MFMA/wave; lanes lr<8 own rows (row2).
// X staged in LDS via global_load_lds (double-buffered per 8 steps); h
// flushed from LDS hist once per 8 steps (coalesced float4).
// ---------------------------------------------------------------------------
__device__ __forceinline__ float pick4(floatx4 v, int r) {
    float x01 = (r & 1) ? v[1] : v[0];
    float x23 = (r & 1) ? v[3] : v[2];
    return (r & 2) ? x23 : x01;
}

__global__ __launch_bounds__(512, 2) void gru_rec(
    const float* __restrict__ Wz,
    const float* __restrict__ Wr,
    const float* __restrict__ Wm,
    const _Float16* __restrict__ Xz,
    const _Float16* __restrict__ Xr,
    float* __restrict__ out)   // holds Xm on entry per row; overwritten with h
{
    const int b = blockIdx.x;
    const int t = threadIdx.x;
    const int w    = t >> 6;        // wave 0..7
    const int lane = t & 63;
    const int lr   = lane & 15;     // D column / A row-in-tile
    const int lq   = lane >> 4;     // D row-quad / A k-octet

    __shared__ __align__(16) _Float16 hh[256];   // h as f16 (MFMA B operand)
    __shared__ __align__(16) float    hf[256];   // h master fp32
    __shared__ __align__(16) _Float16 rh[256];   // r*h as f16
    __shared__ __align__(16) float    zl[256];   // z gate values
    __shared__ __align__(16) _Float16 xzS[4096]; // 2 bufs x 8 rows x 256 (8 KB)
    __shared__ __align__(16) _Float16 xrS[4096]; // 8 KB
    __shared__ __align__(16) float    xmS[4096]; // 16 KB
    __shared__ __align__(16) float    hist[2048];// 8 steps x 256 h rows (8 KB)

    // ---- load recurrent-weight A fragments into registers (fp32 -> f16) ----
    half8_t af[4][8];   // phase A: gate w>>2, m-tiles (w&3)*4 + i
    {
        const float* Wg = (w < 4) ? Wz : Wr;
        #pragma unroll
        for (int i = 0; i < 4; ++i) {
            const float* rp = Wg +
                (size_t)(((w & 3) * 4 + i) * 16 + lr) * (E_DIM + H_DIM) +
                E_DIM + lq * 8;
            #pragma unroll
            for (int kt = 0; kt < 8; ++kt) {
                float4 f0 = *(const float4*)(rp + kt * 32);
                float4 f1 = *(const float4*)(rp + kt * 32 + 4);
                half8_t hv;
                hv[0] = (_Float16)f0.x; hv[1] = (_Float16)f0.y;
                hv[2] = (_Float16)f0.z; hv[3] = (_Float16)f0.w;
                hv[4] = (_Float16)f1.x; hv[5] = (_Float16)f1.y;
                hv[6] = (_Float16)f1.z; hv[7] = (_Float16)f1.w;
                af[i][kt] = hv;
            }
        }
    }
    half8_t am[2][8];   // phase B: m gate, m-tiles w*2 + i
    {
        #pragma unroll
        for (int i = 0; i < 2; ++i) {
            const float* rp = Wm +
                (size_t)((w * 2 + i) * 16 + lr) * (E_DIM + H_DIM) +
                E_DIM + lq * 8;
            #pragma unroll
            for (int kt = 0; kt < 8; ++kt) {
                float4 f0 = *(const float4*)(rp + kt * 32);
                float4 f1 = *(const float4*)(rp + kt * 32 + 4);
                half8_t hv;
                hv[0] = (_Float16)f0.x; hv[1] = (_Float16)f0.y;
                hv[2] = (_Float16)f0.z; hv[3] = (_Float16)f0.w;
                hv[4] = (_Float16)f1.x; hv[5] = (_Float16)f1.y;
                hv[6] = (_Float16)f1.z; hv[7] = (_Float16)f1.w;
                am[i][kt] = hv;
            }
        }
    }

    // per-lane output-row ownership (one row per lane)
    //   phase A: i = lr>>2, r = lr&3 -> row in [ (w&3)*64 , +64 )
    const int rowA = (w & 3) * 64 + (lr >> 2) * 16 + lq * 4 + (lr & 3);
    //   phase B: i = (lr>>2)&1, r = lr&3, active lanes lr<8 -> row in [w*32,+32)
    const int row2 = w * 32 + ((lr >> 2) & 1) * 16 + lq * 4 + (lr & 3);

    const size_t rowbase = (size_t)b * T_DIM * H_DIM;
    const _Float16* XgS = (w < 4) ? xzS : xrS;   // LDS stage source per wave

    // stage rows [row0, row0+8) of Xz/Xr/out into LDS buffer `buf`.
    // 16 x 1KB DMA chunks, 2 per wave (wave-uniform branch).
    auto stage_block = [&](int row0, int buf) {
        const size_t base = rowbase + (size_t)row0 * H_DIM;  // element offset
        #pragma unroll
        for (int qq = 0; qq < 2; ++qq) {
            const int q = w * 2 + qq;
            if (q < 4)
                dma1k(Xz + base + q * 512,
                      (void*)(xzS + buf * 2048 + q * 512), lane);
            else if (q < 8)
                dma1k(Xr + base + (q - 4) * 512,
                      (void*)(xrS + buf * 2048 + (q - 4) * 512), lane);
            else
                dma1k(out + base + (q - 8) * 256,
                      (void*)(xmS + buf * 2048 + (q - 8) * 256), lane);
        }
    };

    stage_block(0, 0);                       // rows 0..7 -> buf 0
    if (t < 256) { hh[t] = (_Float16)0.0f; hf[t] = 0.0f; }
    __syncthreads();                         // drains prologue DMA (once)

    for (int ts8 = 0; ts8 < T_DIM; ts8 += 8) {
        const int cur = (ts8 >> 3) & 1;
        #pragma unroll
        for (int j = 0; j < 8; ++j) {
            // issue next block's staging early in step 7; drained (hidden)
            // under this step's phase-A MFMAs at the phase-A barrier.
            if (j == 7 && ts8 + 8 < T_DIM)
                stage_block(ts8 + 8, cur ^ 1);

            // ---- phase A: (Wz_h.h | Wr_h.h) via MFMA, then sigmoid ----
            floatx4 acc[4];
            acc[0] = (floatx4)0.0f; acc[1] = (floatx4)0.0f;
            acc[2] = (floatx4)0.0f; acc[3] = (floatx4)0.0f;
            #pragma unroll
            for (int kt = 0; kt < 8; ++kt) {
                half8_t bf = *(const half8_t*)&hh[kt * 32 + lq * 8]; // bcast/lq
                #pragma unroll
                for (int i = 0; i < 4; ++i)
                    acc[i] = __builtin_amdgcn_mfma_f32_16x16x32_f16(
                        af[i][kt], bf, acc[i], 0, 0, 0);
            }
            {
                const int r = lr & 3;
                float s0 = pick4(acc[0], r), s1 = pick4(acc[1], r);
                float s2 = pick4(acc[2], r), s3 = pick4(acc[3], r);
                float v = (lr & 8) ? ((lr & 4) ? s3 : s2)
                                   : ((lr & 4) ? s1 : s0);
                const float a = v + (float)XgS[cur * 2048 + j * 256 + rowA];
                const float g = 1.0f / (1.0f + __expf(-a));
                if (w < 4) zl[rowA] = g;                        // z
                else       rh[rowA] = (_Float16)(g * hf[rowA]); // r*h
            }
            __syncthreads();

            // ---- phase B: Wm_h.(r*h) via MFMA, then tanh + h update ----
            floatx4 acc2[2];
            acc2[0] = (floatx4)0.0f; acc2[1] = (floatx4)0.0f;
            #pragma unroll
            for (int kt = 0; kt < 8; ++kt) {
                half8_t bfm = *(const half8_t*)&rh[kt * 32 + lq * 8];
                #pragma unroll
                for (int i = 0; i < 2; ++i)
                    acc2[i] = __builtin_amdgcn_mfma_f32_16x16x32_f16(
                        am[i][kt], bfm, acc2[i], 0, 0, 0);
            }
            if (lr < 8) {
                const int r = lr & 3;
                float u0 = pick4(acc2[0], r), u1 = pick4(acc2[1], r);
                float v2 = (lr & 4) ? u1 : u0;
                const float amv = v2 + xmS[cur * 2048 + j * 256 + row2];
                const float hc  = 2.0f / (1.0f + __expf(-2.0f * amv)) - 1.0f;
                const float z   = zl[row2];
                const float hp  = hf[row2];
                const float hn  = hp + z * (hc - hp);
                hist[j * 256 + row2] = hn;
                hf[row2] = hn;
                hh[row2] = (_Float16)hn;
            }
            __syncthreads();
        }

        // ---- batched h flush: hist is the flat image of out rows ts8..+7 ----
        {
            const float4 hv4 = *(const float4*)&hist[t * 4];
            *(float4*)&out[rowbase + (size_t)ts8 * H_DIM + t * 4] = hv4;
        }
    }
}

extern "C" void kernel_launch(void* const* d_in, const int* in_sizes, int n_in,
                              void* d_out, int out_size, void* d_ws, size_t ws_size,
                              hipStream_t stream) {
    (void)in_sizes; (void)n_in; (void)out_size;
    const float* emb = (const float*)d_in[0];
    const float* Wz  = (const float*)d_in[1];
    const float* bz  = (const float*)d_in[2];
    const float* Wr  = (const float*)d_in[3];
    const float* br  = (const float*)d_in[4];
    const float* Wm  = (const float*)d_in[5];
    const float* bm  = (const float*)d_in[6];
    float* out = (float*)d_out;

    _Float16* Xz = (_Float16*)d_ws;                      // [131072][256] f16
    _Float16* Xr = Xz + (size_t)MROWS * H_DIM;           // [131072][256] f16

    const size_t xBytes = (size_t)MROWS * H_DIM * 2 * 2; // Xz+Xr = 128 MiB
    const size_t wBytes = (size_t)3 * 256 * 512 * 2;     // Wf16 = 768 KiB
    _Float16* Wf16 = (ws_size >= xBytes + wBytes)
                   ? (Xr + (size_t)MROWS * H_DIM) : (_Float16*)nullptr;

    if (Wf16)
        cvt_w<<<dim3(128, 3), 256, 0, stream>>>(Wz, Wr, Wm, Wf16);
    gemm_x<<<dim3(MROWS / 128), 256, 0, stream>>>(
        emb, Wz, bz, Wr, br, Wm, bm, Wf16, Xz, Xr, out);
    gru_rec<<<B_DIM, 512, 0, stream>>>(Wz, Wr, Wm, Xz, Xr, out);
}